// Round 10
// baseline (409.015 us; speedup 1.0000x reference)
//
#include <hip/hip_runtime.h>

#define N_NODES 100000
#define N_EDGES 1600000
#define IN_CH   64
#define HID_CH  64
#define OUT_CH  128

typedef __attribute__((ext_vector_type(8))) __bf16    bf16x8;
typedef __attribute__((ext_vector_type(4))) float     f32x4;
typedef __attribute__((ext_vector_type(2))) _Float16  f16x2;
typedef __attribute__((ext_vector_type(8))) _Float16  f16x8;

__device__ __forceinline__ unsigned short f2bf(float f) {
    union { float f; unsigned int i; } c;
    c.f = f;
    unsigned int u = c.i;
    unsigned int r = (u + 0x7FFFu + ((u >> 16) & 1u)) >> 16;   // RNE
    return (unsigned short)r;
}

// packed fp16 atomic add (global_atomic_pk_add_f16)
__device__ __forceinline__ void atomic_pk_add_f16(unsigned int* addr, f16x2 val) {
    typedef __attribute__((address_space(1))) f16x2 gf16x2;
    __builtin_amdgcn_global_atomic_fadd_v2f16((gf16x2*)(void*)addr, val);
}

__device__ __forceinline__ bool edge_mask(int ntc, float a0) {
    if (ntc == 0) return a0 < 0.5f;
    if (ntc == 1) return a0 < 0.3f;
    return true;
}

// ---------- fused prep + hist (1.6M threads; both jobs per thread) ----------
// job A: convert x vec4 #i -> xb, derive ntype byte table for scatter.
// job B: edge #i: mask (reads x[src*64] directly, fp32, L3-served) ->
//        deg histogram atomic. deg pre-zeroed by hipMemsetAsync.
__global__ void gnn_prep_hist(const float* __restrict__ xf,
                              unsigned short* __restrict__ xb,
                              unsigned char* __restrict__ ntype,
                              const int* __restrict__ eidx,
                              const float* __restrict__ ea,
                              int* __restrict__ deg) {
    int i = blockIdx.x * blockDim.x + threadIdx.x;   // exactly 1.6M, no guard
    // --- job A ---
    float4 v = reinterpret_cast<const float4*>(xf)[i];
    ushort4 o;
    o.x = f2bf(v.x); o.y = f2bf(v.y); o.z = f2bf(v.z); o.w = f2bf(v.w);
    reinterpret_cast<ushort4*>(xb)[i] = o;
    if ((i & 15) == 0)
        ntype[i >> 4] = (v.x == 0.0f) ? 0 : ((v.x == 1.0f) ? 1 : 2);
    // --- job B ---
    int s = eidx[i];
    int d = eidx[N_EDGES + i];
    float a0 = ea[i * 3];
    float nt = xf[(size_t)s * IN_CH];
    bool mk = (nt == 0.0f) ? (a0 < 0.5f) : ((nt == 1.0f) ? (a0 < 0.3f) : true);
    if (mk) atomicAdd(&deg[d], 1);
}

// ---------- 3-phase exclusive scan of deg[100K] (verified R7/R9) ----------
__global__ void gnn_scanA(const int* __restrict__ deg,
                          int* __restrict__ tmp, int* __restrict__ bsum) {
    __shared__ int s[256];
    int i = blockIdx.x * 256 + threadIdx.x;
    int v = (i < N_NODES) ? deg[i] : 0;
    s[threadIdx.x] = v;
    for (int o = 1; o < 256; o <<= 1) {
        __syncthreads();
        int u = (threadIdx.x >= o) ? s[threadIdx.x - o] : 0;
        __syncthreads();
        s[threadIdx.x] += u;
    }
    __syncthreads();
    if (i < N_NODES) tmp[i] = s[threadIdx.x];          // inclusive
    if (threadIdx.x == 255) bsum[blockIdx.x] = s[255];
}
__global__ void gnn_scanB(const int* __restrict__ bsum, int* __restrict__ boff,
                          int nblk) {
    __shared__ int s[512];
    int t = threadIdx.x;
    int v = (t < nblk) ? bsum[t] : 0;
    s[t] = v;
    for (int o = 1; o < 512; o <<= 1) {
        __syncthreads();
        int u = (t >= o) ? s[t - o] : 0;
        __syncthreads();
        s[t] += u;
    }
    __syncthreads();
    if (t < nblk) boff[t] = s[t] - v;                  // exclusive
}
__global__ void gnn_scanC(const int* __restrict__ tmp, const int* __restrict__ deg,
                          const int* __restrict__ boff, int* __restrict__ off) {
    int i = blockIdx.x * 256 + threadIdx.x;
    if (i < N_NODES) off[i] = tmp[i] - deg[i] + boff[blockIdx.x];  // exclusive
}

// ---------- scatter: masked edges -> 8B records sorted by dst (R9) ----------
// rec.x = src | a0q<<17 | (a1q&31)<<27 ; rec.y = dst | (a1q>>5)<<17 | a2q<<22
// off[] consumed destructively: afterwards off[d] = inclusive end of d's run.
__global__ void gnn_scatter(const int* __restrict__ eidx,
                            const float* __restrict__ ea,
                            const unsigned char* __restrict__ ntype,
                            int* __restrict__ off,
                            uint2* __restrict__ rec) {
    int e = blockIdx.x * blockDim.x + threadIdx.x;
    if (e >= N_EDGES) return;
    int s = eidx[e];
    int d = eidx[N_EDGES + e];
    float a0 = ea[e * 3], a1 = ea[e * 3 + 1], a2 = ea[e * 3 + 2];
    if (!edge_mask(ntype[s], a0)) return;
    int pos = atomicAdd(&off[d], 1);
    unsigned a0q = (unsigned)(a0 * 1023.0f + 0.5f);
    unsigned a1q = (unsigned)(a1 * 1023.0f + 0.5f);
    unsigned a2q = (unsigned)(a2 * 1023.0f + 0.5f);
    uint2 r;
    r.x = (unsigned)s | (a0q << 17) | ((a1q & 31u) << 27);
    r.y = (unsigned)d | ((a1q >> 5) << 17) | (a2q << 22);
    rec[pos] = r;
}

// ---------- edge kernel: per-wave barrier-free MFMA over sorted records ----
// Every staged value (srcs/dsts/eas of a 32-record chunk) is consumed ONLY by
// the owning wave, so R9's two per-tile __syncthreads protected nothing:
// lanes 0..31 decode rec into a per-wave LDS slice; same-wave lgkm ordering
// (verified R4 H2-roundtrip pattern) suffices. Waves are independent
// grid-stride workers -> no barrier stalls, no idle staging lanes.
// Epilogue unchanged from R9: relu -> pk-f16 atomics, same-dst run combining.
__global__ __launch_bounds__(256, 6) void gnn_edge_sorted(
    const unsigned short* __restrict__ xb,    // [N_NODES][64] bf16 bits
    const uint2*          __restrict__ rec,   // dst-sorted packed edges
    const int*            __restrict__ off,   // inclusive ends; off[N-1]=M
    const float*          __restrict__ W1,    // [131][64]
    const float*          __restrict__ b1,    // [64]
    unsigned int*         __restrict__ hsum)  // [N_NODES][32] f16 pairs
{
    __shared__ __align__(16) unsigned short W1T[64][136];   // 17.4KB
    __shared__ float w1tail[4][64];                          // 1KB
    __shared__ float eas[4][32][4];                          // per-wave 2KB
    __shared__ int   srcs[4][32];
    __shared__ int   dabs[4][32];    // dst or 0 (pad rows)
    __shared__ int   dsts[4][32];    // dst or -1 (pad rows)

    const int tid  = threadIdx.x;
    const int wave = tid >> 6;
    const int lane = tid & 63;
    const int q    = lane >> 4;
    const int m16  = lane & 15;

    for (int idx = tid; idx < 128 * 64; idx += 256) {
        int k = idx >> 6, n = idx & 63;
        W1T[n][k] = f2bf(W1[idx]);
    }
    if (tid < 64) {
        w1tail[0][tid] = W1[128 * 64 + tid];
        w1tail[1][tid] = W1[129 * 64 + tid];
        w1tail[2][tid] = W1[130 * 64 + tid];
        w1tail[3][tid] = b1[tid];
    }
    __syncthreads();   // once: protect W1T/w1tail staging

    const int M       = off[N_NODES - 1];
    const int nChunks = (M + 31) >> 5;
    const int wstride = gridDim.x * 4;

    for (int c = blockIdx.x * 4 + wave; c < nChunks; c += wstride) {
        const int base = c << 5;

        // ---- per-wave staging: lanes 0..31 decode one record each ----
        if (lane < 32) {
            int e = base + lane;
            if (e < M) {
                uint2 r = rec[e];
                int s = (int)(r.x & 0x1FFFFu);
                int d = (int)(r.y & 0x1FFFFu);
                srcs[wave][lane] = s; dabs[wave][lane] = d; dsts[wave][lane] = d;
                const float dq = 1.0f / 1023.0f;
                eas[wave][lane][0] = (float)((r.x >> 17) & 1023u) * dq;
                eas[wave][lane][1] = (float)(((r.x >> 27) & 31u) |
                                             (((r.y >> 17) & 31u) << 5)) * dq;
                eas[wave][lane][2] = (float)((r.y >> 22) & 1023u) * dq;
            } else {
                srcs[wave][lane] = 0; dabs[wave][lane] = 0; dsts[wave][lane] = -1;
                eas[wave][lane][0] = 0.f; eas[wave][lane][1] = 0.f;
                eas[wave][lane][2] = 0.f;
            }
        }
        // no barrier: same-wave ds_write -> ds_read ordering via lgkmcnt

        // ---- acc init: b1 + ea @ W1[128:131] (fp32 VALU) ----
        f32x4 acc1[2][4];
#pragma unroll
        for (int mt = 0; mt < 2; ++mt) {
            float e0[4], e1[4], e2[4];
#pragma unroll
            for (int r = 0; r < 4; ++r) {
                int el = mt * 16 + q * 4 + r;           // C-layout row in [0,32)
                e0[r] = eas[wave][el][0]; e1[r] = eas[wave][el][1];
                e2[r] = eas[wave][el][2];
            }
#pragma unroll
            for (int nt = 0; nt < 4; ++nt) {
                int n = nt * 16 + m16;                  // C-layout col
                float t0 = w1tail[0][n], t1 = w1tail[1][n];
                float t2 = w1tail[2][n], bb = w1tail[3][n];
#pragma unroll
                for (int r = 0; r < 4; ++r)
                    acc1[mt][nt][r] = bb + e0[r] * t0 + e1[r] * t1 + e2[r] * t2;
            }
        }

        // ---- K=128 over [x_dst | x_src]; dst gathers broadcast-heavy ----
#pragma unroll
        for (int kc = 0; kc < 4; ++kc) {
            bf16x8 af[2];
#pragma unroll
            for (int mt = 0; mt < 2; ++mt) {
                int el   = mt * 16 + m16;               // A-layout row in [0,32)
                int node = (kc < 2) ? dabs[wave][el] : srcs[wave][el];
                af[mt] = *reinterpret_cast<const bf16x8*>(
                    xb + (size_t)node * IN_CH + (kc & 1) * 32 + q * 8);
            }
#pragma unroll
            for (int nt = 0; nt < 4; ++nt) {
                bf16x8 bfr = *reinterpret_cast<const bf16x8*>(
                    &W1T[nt * 16 + m16][kc * 32 + q * 8]);
                acc1[0][nt] = __builtin_amdgcn_mfma_f32_16x16x32_bf16(af[0], bfr, acc1[0][nt], 0, 0, 0);
                acc1[1][nt] = __builtin_amdgcn_mfma_f32_16x16x32_bf16(af[1], bfr, acc1[1][nt], 0, 0, 0);
            }
        }

        // ---- epilogue: relu -> pk-f16 atomics with same-dst combining ----
        // hsum channel permutation pi: dword d<16 -> ch (d,d+16);
        // d>=16 -> ch (d+16,d+32). Node kernel stages W2 rows with same pi.
#pragma unroll
        for (int mt = 0; mt < 2; ++mt) {
            int dd[4];
            float v[4][4];
#pragma unroll
            for (int r = 0; r < 4; ++r)
                dd[r] = dsts[wave][mt * 16 + q * 4 + r];
#pragma unroll
            for (int nt = 0; nt < 4; ++nt)
#pragma unroll
                for (int r = 0; r < 4; ++r) {
                    float w = acc1[mt][nt][r];
                    v[nt][r] = w > 0.0f ? w : 0.0f;
                }
            bool same = (dd[0] == dd[1]) && (dd[0] == dd[2]) && (dd[0] == dd[3]);
            if (same && dd[0] >= 0) {
                unsigned int* hbase = hsum + (size_t)dd[0] * 32;
                float s0 = (v[0][0] + v[0][1]) + (v[0][2] + v[0][3]);
                float s1 = (v[1][0] + v[1][1]) + (v[1][2] + v[1][3]);
                float s2 = (v[2][0] + v[2][1]) + (v[2][2] + v[2][3]);
                float s3 = (v[3][0] + v[3][1]) + (v[3][2] + v[3][3]);
                if (s0 + s1 > 0.f)
                    atomic_pk_add_f16(hbase + m16, (f16x2){(_Float16)s0, (_Float16)s1});
                if (s2 + s3 > 0.f)
                    atomic_pk_add_f16(hbase + 16 + m16, (f16x2){(_Float16)s2, (_Float16)s3});
            } else {
#pragma unroll
                for (int r = 0; r < 4; ++r) {
                    if (dd[r] >= 0) {
                        unsigned int* hbase = hsum + (size_t)dd[r] * 32;
                        if (v[0][r] + v[1][r] > 0.f)
                            atomic_pk_add_f16(hbase + m16,
                                (f16x2){(_Float16)v[0][r], (_Float16)v[1][r]});
                        if (v[2][r] + v[3][r] > 0.f)
                            atomic_pk_add_f16(hbase + 16 + m16,
                                (f16x2){(_Float16)v[2][r], (_Float16)v[3][r]});
                    }
                }
            }
        }
    }
}

// ---------- node kernel: out = relu(hsum @ W2 + deg*b2), MFMA ----------
__global__ __launch_bounds__(256, 4) void gnn_node_out(
    const _Float16* __restrict__ hsum,  // [N_NODES][64] f16, permuted channels
    const int*      __restrict__ deg,   // [N_NODES]
    const float*    __restrict__ W2,    // [64][128]
    const float*    __restrict__ b2,    // [128]
    float*          __restrict__ out)   // [N_NODES][128]
{
    __shared__ __align__(16) unsigned short W2T[128][72];  // W2T[n][p]=W2[pi(p)][n]
    __shared__ float b2s[128];

    const int tid  = threadIdx.x;
    const int wave = tid >> 6;
    const int lane = tid & 63;
    const int q    = lane >> 4;
    const int m16  = lane & 15;

    for (int idx = tid; idx < 64 * 128; idx += 256) {
        int p = idx >> 7, n = idx & 127;
        // pi(p): dword d=p>>1, half e=p&1; d<16 -> ch d+16e; d>=16 -> d+16+16e
        int ch = (p >> 1) + 16 * (p & 1) + ((p >= 32) ? 16 : 0);
        W2T[n][p] = f2bf(W2[ch * 128 + n]);
    }
    if (tid < 128) b2s[tid] = b2[tid];
    __syncthreads();

    const int nodeBase = (blockIdx.x * 4 + wave) * 32;
    if (nodeBase >= N_NODES) return;

    f32x4 acc[2][8];
#pragma unroll
    for (int mt = 0; mt < 2; ++mt)
#pragma unroll
        for (int nt = 0; nt < 8; ++nt)
            acc[mt][nt] = (f32x4){0.0f, 0.0f, 0.0f, 0.0f};

#pragma unroll
    for (int kc = 0; kc < 2; ++kc) {
        bf16x8 af[2];
#pragma unroll
        for (int mt = 0; mt < 2; ++mt) {
            int node = nodeBase + mt * 16 + m16;
            if (node >= N_NODES) node = N_NODES - 1;
            f16x8 h = *reinterpret_cast<const f16x8*>(
                hsum + (size_t)node * HID_CH + kc * 32 + q * 8);
            union { bf16x8 v; unsigned short u[8]; } rr;
#pragma unroll
            for (int j = 0; j < 8; ++j) rr.u[j] = f2bf((float)h[j]);
            af[mt] = rr.v;
        }
#pragma unroll
        for (int nt = 0; nt < 8; ++nt) {
            bf16x8 bfr = *reinterpret_cast<const bf16x8*>(
                &W2T[nt * 16 + m16][kc * 32 + q * 8]);
            acc[0][nt] = __builtin_amdgcn_mfma_f32_16x16x32_bf16(af[0], bfr, acc[0][nt], 0, 0, 0);
            acc[1][nt] = __builtin_amdgcn_mfma_f32_16x16x32_bf16(af[1], bfr, acc[1][nt], 0, 0, 0);
        }
    }

#pragma unroll
    for (int mt = 0; mt < 2; ++mt) {
        float cc[4]; int nn[4];
#pragma unroll
        for (int r = 0; r < 4; ++r) {
            nn[r] = nodeBase + mt * 16 + q * 4 + r;
            cc[r] = (nn[r] < N_NODES) ? (float)deg[nn[r]] : 0.0f;
        }
#pragma unroll
        for (int nt = 0; nt < 8; ++nt) {
            int col = nt * 16 + m16;
            float bb = b2s[col];
#pragma unroll
            for (int r = 0; r < 4; ++r) {
                if (nn[r] < N_NODES) {
                    float v = acc[mt][nt][r] + cc[r] * bb;
                    out[(size_t)nn[r] * OUT_CH + col] = v > 0.0f ? v : 0.0f;
                }
            }
        }
    }
}

extern "C" void kernel_launch(void* const* d_in, const int* in_sizes, int n_in,
                              void* d_out, int out_size, void* d_ws, size_t ws_size,
                              hipStream_t stream) {
    const float* x  = (const float*)d_in[0];
    const int*   ei = (const int*)d_in[1];
    const float* ea = (const float*)d_in[2];
    const float* W1 = (const float*)d_in[3];
    const float* b1 = (const float*)d_in[4];
    const float* W2 = (const float*)d_in[5];
    const float* b2 = (const float*)d_in[6];
    float* out = (float*)d_out;

    // ws layout (bytes):
    // deg @0 (400,000) | hsum @400,000 (12.8M)  <- one contiguous memset
    // xb @13,200,000 (12.8M) | ntype @26,000,000 (100K)
    // off @26,100,096 | tmp @26,500,096 | bsum @26,900,096 | boff @26,902,144
    // rec @26,904,192 (12.8M)  -> total 39.7MB (same as R9)
    char* wsb = (char*)d_ws;
    int*            deg   = (int*)(wsb);
    unsigned int*   hsumU = (unsigned int*)(wsb + 400000);
    unsigned short* xb    = (unsigned short*)(wsb + 13200000);
    unsigned char*  ntype = (unsigned char*)(wsb + 26000000);
    int*            off   = (int*)(wsb + 26100096);
    int*            tmp   = (int*)(wsb + 26500096);
    int*            bsum  = (int*)(wsb + 26900096);
    int*            boff  = (int*)(wsb + 26902144);
    uint2*          rec   = (uint2*)(wsb + 26904192);

    const int nScanBlk = (N_NODES + 255) / 256;   // 391

    // zero deg + hsum in one shot (ws re-poisoned to 0xAA before every call)
    hipMemsetAsync(wsb, 0, 13200000, stream);

    // fused x-convert + ntype table + masked-degree histogram
    gnn_prep_hist<<<N_EDGES / 256, 256, 0, stream>>>(x, xb, ntype, ei, ea, deg);

    gnn_scanA<<<nScanBlk, 256, 0, stream>>>(deg, tmp, bsum);
    gnn_scanB<<<1, 512, 0, stream>>>(bsum, boff, nScanBlk);
    gnn_scanC<<<nScanBlk, 256, 0, stream>>>(tmp, deg, boff, off);
    gnn_scatter<<<(N_EDGES + 255) / 256, 256, 0, stream>>>(ei, ea, ntype, off, rec);

    // barrier-free per-wave edge kernel: 1536 blocks = 6/CU (22KB LDS)
    gnn_edge_sorted<<<1536, 256, 0, stream>>>(xb, rec, off, W1, b1, hsumU);

    gnn_node_out<<<(N_NODES + 127) / 128, 256, 0, stream>>>(
        (const _Float16*)hsumU, deg, W2, b2, out);
}

// Round 11
// 313.412 us; speedup vs baseline: 1.3050x; 1.3050x over previous
//
#include <hip/hip_runtime.h>

#define N_NODES 100000
#define N_EDGES 1600000
#define IN_CH   64
#define HID_CH  64
#define OUT_CH  128
#define NSCANBLK 391   // ceil(100000/256)

typedef __attribute__((ext_vector_type(8))) __bf16    bf16x8;
typedef __attribute__((ext_vector_type(4))) float     f32x4;
typedef __attribute__((ext_vector_type(2))) _Float16  f16x2;
typedef __attribute__((ext_vector_type(8))) _Float16  f16x8;

__device__ __forceinline__ unsigned short f2bf(float f) {
    union { float f; unsigned int i; } c;
    c.f = f;
    unsigned int u = c.i;
    unsigned int r = (u + 0x7FFFu + ((u >> 16) & 1u)) >> 16;   // RNE
    return (unsigned short)r;
}

// packed fp16 atomic add (global_atomic_pk_add_f16)
__device__ __forceinline__ void atomic_pk_add_f16(unsigned int* addr, f16x2 val) {
    typedef __attribute__((address_space(1))) f16x2 gf16x2;
    __builtin_amdgcn_global_atomic_fadd_v2f16((gf16x2*)(void*)addr, val);
}

__device__ __forceinline__ bool edge_mask(int ntc, float a0) {
    if (ntc == 0) return a0 < 0.5f;
    if (ntc == 1) return a0 < 0.3f;
    return true;
}

// ---------- fused prep + hist + hsum-zero (1.6M threads) ----------
// job A: convert x vec4 #i -> xb; ntype byte table.
// job B: edge #i mask (reads x[src*64] fp32) -> deg histogram atomic.
// job C: zero hsum uint2 #i (12.8MB). deg/scan-state zeroed by memsetAsync.
__global__ void gnn_prep_hist(const float* __restrict__ xf,
                              unsigned short* __restrict__ xb,
                              unsigned char* __restrict__ ntype,
                              const int* __restrict__ eidx,
                              const float* __restrict__ ea,
                              int* __restrict__ deg,
                              uint2* __restrict__ hz) {
    int i = blockIdx.x * blockDim.x + threadIdx.x;   // exactly 1.6M, no guard
    // --- job C ---
    hz[i] = (uint2){0u, 0u};
    // --- job A ---
    float4 v = reinterpret_cast<const float4*>(xf)[i];
    ushort4 o;
    o.x = f2bf(v.x); o.y = f2bf(v.y); o.z = f2bf(v.z); o.w = f2bf(v.w);
    reinterpret_cast<ushort4*>(xb)[i] = o;
    if ((i & 15) == 0)
        ntype[i >> 4] = (v.x == 0.0f) ? 0 : ((v.x == 1.0f) ? 1 : 2);
    // --- job B ---
    int s = eidx[i];
    int d = eidx[N_EDGES + i];
    float a0 = ea[i * 3];
    float nt = xf[(size_t)s * IN_CH];
    bool mk = (nt == 0.0f) ? (a0 < 0.5f) : ((nt == 1.0f) ? (a0 < 0.3f) : true);
    if (mk) atomicAdd(&deg[d], 1);
}

// ---------- single-pass exclusive scan (decoupled lookback) ----------
// Replaces scanA/B/C (3 dispatches -> 1). st[b] packs (state<<32)|value:
// state 0=empty, 1=aggregate, 2=inclusive. Ticket ordering makes the spin
// safe: a block only waits on lower tickets, which are already executing,
// and each publishes its aggregate before any wait of its own.
__global__ void gnn_scan1(const int* __restrict__ deg,
                          int* __restrict__ off,
                          unsigned long long* __restrict__ st,
                          int* __restrict__ ticket) {
    __shared__ int s[256];
    __shared__ int bid_s, excl_s;
    const int tid = threadIdx.x;
    if (tid == 0) bid_s = atomicAdd(ticket, 1);
    __syncthreads();
    const int b = bid_s;
    const int i = b * 256 + tid;
    int v = (i < N_NODES) ? deg[i] : 0;
    s[tid] = v;
    for (int o = 1; o < 256; o <<= 1) {
        __syncthreads();
        int u = (tid >= o) ? s[tid - o] : 0;
        __syncthreads();
        s[tid] += u;
    }
    __syncthreads();
    const int incl  = s[tid];
    const int total = s[255];
    if (tid == 0) {
        if (b == 0) {
            atomicExch(&st[0], (2ULL << 32) | (unsigned)total);
            excl_s = 0;
        } else {
            atomicExch(&st[b], (1ULL << 32) | (unsigned)total);
            int excl = 0;
            int j = b - 1;
            while (true) {
                unsigned long long p = atomicAdd(&st[j], 0ULL);  // device-scope read
                unsigned stt = (unsigned)(p >> 32);
                if (stt == 0) continue;          // predecessor not published yet
                excl += (int)(p & 0xFFFFFFFFULL);
                if (stt == 2) break;             // hit an inclusive prefix
                --j;
            }
            atomicExch(&st[b], (2ULL << 32) | (unsigned)(excl + total));
            excl_s = excl;
        }
    }
    __syncthreads();
    if (i < N_NODES) off[i] = incl - v + excl_s;   // exclusive prefix
}

// ---------- scatter: masked edges -> 8B records sorted by dst (R9) ----------
// rec.x = src | a0q<<17 | (a1q&31)<<27 ; rec.y = dst | (a1q>>5)<<17 | a2q<<22
// off[] consumed destructively: afterwards off[d] = inclusive end of d's run.
__global__ void gnn_scatter(const int* __restrict__ eidx,
                            const float* __restrict__ ea,
                            const unsigned char* __restrict__ ntype,
                            int* __restrict__ off,
                            uint2* __restrict__ rec) {
    int e = blockIdx.x * blockDim.x + threadIdx.x;
    if (e >= N_EDGES) return;
    int s = eidx[e];
    int d = eidx[N_EDGES + e];
    float a0 = ea[e * 3], a1 = ea[e * 3 + 1], a2 = ea[e * 3 + 2];
    if (!edge_mask(ntype[s], a0)) return;
    int pos = atomicAdd(&off[d], 1);
    unsigned a0q = (unsigned)(a0 * 1023.0f + 0.5f);
    unsigned a1q = (unsigned)(a1 * 1023.0f + 0.5f);
    unsigned a2q = (unsigned)(a2 * 1023.0f + 0.5f);
    uint2 r;
    r.x = (unsigned)s | (a0q << 17) | ((a1q & 31u) << 27);
    r.y = (unsigned)d | ((a1q >> 5) << 17) | (a2q << 22);
    rec[pos] = r;
}

// ---------- edge kernel: EXACT R9 (block-tile, lockstep barriers) ----------
// R10 proved the per-tile __syncthreads are load-bearing: they keep the 4
// waves temporally clustered on the sorted stream so L2 combines same-line
// atomics/gathers (R10 barrier-free: FETCH 50->410MB, 2.2x slower).
__global__ __launch_bounds__(256, 4) void gnn_edge_sorted(
    const unsigned short* __restrict__ xb,    // [N_NODES][64] bf16 bits
    const uint2*          __restrict__ rec,   // dst-sorted packed edges
    const int*            __restrict__ off,   // inclusive ends; off[N-1]=M
    const float*          __restrict__ W1,    // [131][64]
    const float*          __restrict__ b1,    // [64]
    unsigned int*         __restrict__ hsum)  // [N_NODES][32] f16 pairs
{
    __shared__ __align__(16) unsigned short W1T[64][136];
    __shared__ float w1tail[4][64];
    __shared__ float eas[128][4];
    __shared__ int   srcs[128];
    __shared__ int   dabs[128];    // dst or 0 (pad)
    __shared__ int   dsts[128];    // dst or -1 (pad)

    const int tid  = threadIdx.x;
    const int wave = tid >> 6;
    const int lane = tid & 63;
    const int q    = lane >> 4;
    const int m16  = lane & 15;

    for (int idx = tid; idx < 128 * 64; idx += 256) {
        int k = idx >> 6, n = idx & 63;
        W1T[n][k] = f2bf(W1[idx]);
    }
    if (tid < 64) {
        w1tail[0][tid] = W1[128 * 64 + tid];
        w1tail[1][tid] = W1[129 * 64 + tid];
        w1tail[2][tid] = W1[130 * 64 + tid];
        w1tail[3][tid] = b1[tid];
    }

    const int M      = off[N_NODES - 1];
    const int nTiles = (M + 127) >> 7;

    for (int t = blockIdx.x; t < nTiles; t += gridDim.x) {
        __syncthreads();   // LDS WAR (and 1st-iter weight staging)
        if (tid < 128) {
            int e = (t << 7) + tid;
            if (e < M) {
                uint2 r = rec[e];
                int s = (int)(r.x & 0x1FFFFu);
                int d = (int)(r.y & 0x1FFFFu);
                srcs[tid] = s; dabs[tid] = d; dsts[tid] = d;
                const float dq = 1.0f / 1023.0f;
                eas[tid][0] = (float)((r.x >> 17) & 1023u) * dq;
                eas[tid][1] = (float)(((r.x >> 27) & 31u) | (((r.y >> 17) & 31u) << 5)) * dq;
                eas[tid][2] = (float)((r.y >> 22) & 1023u) * dq;
            } else {
                srcs[tid] = 0; dabs[tid] = 0; dsts[tid] = -1;
                eas[tid][0] = 0.f; eas[tid][1] = 0.f; eas[tid][2] = 0.f;
            }
        }
        __syncthreads();

        const int ebase = wave * 32;

        // acc init: b1 + ea @ W1[128:131] (fp32 VALU)
        f32x4 acc1[2][4];
#pragma unroll
        for (int mt = 0; mt < 2; ++mt) {
            float e0[4], e1[4], e2[4];
#pragma unroll
            for (int r = 0; r < 4; ++r) {
                int el = ebase + mt * 16 + q * 4 + r;   // C-layout row
                e0[r] = eas[el][0]; e1[r] = eas[el][1]; e2[r] = eas[el][2];
            }
#pragma unroll
            for (int nt = 0; nt < 4; ++nt) {
                int n = nt * 16 + m16;                  // C-layout col
                float t0 = w1tail[0][n], t1 = w1tail[1][n];
                float t2 = w1tail[2][n], bb = w1tail[3][n];
#pragma unroll
                for (int r = 0; r < 4; ++r)
                    acc1[mt][nt][r] = bb + e0[r] * t0 + e1[r] * t1 + e2[r] * t2;
            }
        }

        // K=128 over [x_dst | x_src]; dst loads broadcast-heavy (sorted)
#pragma unroll
        for (int kc = 0; kc < 4; ++kc) {
            bf16x8 af[2];
#pragma unroll
            for (int mt = 0; mt < 2; ++mt) {
                int el   = ebase + mt * 16 + m16;       // A-layout row
                int node = (kc < 2) ? dabs[el] : srcs[el];
                af[mt] = *reinterpret_cast<const bf16x8*>(
                    xb + (size_t)node * IN_CH + (kc & 1) * 32 + q * 8);
            }
#pragma unroll
            for (int nt = 0; nt < 4; ++nt) {
                bf16x8 bfr = *reinterpret_cast<const bf16x8*>(
                    &W1T[nt * 16 + m16][kc * 32 + q * 8]);
                acc1[0][nt] = __builtin_amdgcn_mfma_f32_16x16x32_bf16(af[0], bfr, acc1[0][nt], 0, 0, 0);
                acc1[1][nt] = __builtin_amdgcn_mfma_f32_16x16x32_bf16(af[1], bfr, acc1[1][nt], 0, 0, 0);
            }
        }

        // epilogue: relu -> pk-f16 atomics with same-dst run combining.
        // hsum channel permutation pi: dword d<16 -> ch (d,d+16);
        // d>=16 -> ch (d+16,d+32). Node kernel stages W2 rows with same pi.
#pragma unroll
        for (int mt = 0; mt < 2; ++mt) {
            int dd[4];
            float v[4][4];
#pragma unroll
            for (int r = 0; r < 4; ++r)
                dd[r] = dsts[ebase + mt * 16 + q * 4 + r];
#pragma unroll
            for (int nt = 0; nt < 4; ++nt)
#pragma unroll
                for (int r = 0; r < 4; ++r) {
                    float w = acc1[mt][nt][r];
                    v[nt][r] = w > 0.0f ? w : 0.0f;
                }
            bool same = (dd[0] == dd[1]) && (dd[0] == dd[2]) && (dd[0] == dd[3]);
            if (same && dd[0] >= 0) {
                unsigned int* hbase = hsum + (size_t)dd[0] * 32;
                float s0 = (v[0][0] + v[0][1]) + (v[0][2] + v[0][3]);
                float s1 = (v[1][0] + v[1][1]) + (v[1][2] + v[1][3]);
                float s2 = (v[2][0] + v[2][1]) + (v[2][2] + v[2][3]);
                float s3 = (v[3][0] + v[3][1]) + (v[3][2] + v[3][3]);
                if (s0 + s1 > 0.f)
                    atomic_pk_add_f16(hbase + m16, (f16x2){(_Float16)s0, (_Float16)s1});
                if (s2 + s3 > 0.f)
                    atomic_pk_add_f16(hbase + 16 + m16, (f16x2){(_Float16)s2, (_Float16)s3});
            } else {
#pragma unroll
                for (int r = 0; r < 4; ++r) {
                    if (dd[r] >= 0) {
                        unsigned int* hbase = hsum + (size_t)dd[r] * 32;
                        if (v[0][r] + v[1][r] > 0.f)
                            atomic_pk_add_f16(hbase + m16,
                                (f16x2){(_Float16)v[0][r], (_Float16)v[1][r]});
                        if (v[2][r] + v[3][r] > 0.f)
                            atomic_pk_add_f16(hbase + 16 + m16,
                                (f16x2){(_Float16)v[2][r], (_Float16)v[3][r]});
                    }
                }
            }
        }
    }
}

// ---------- node kernel: out = relu(hsum @ W2 + deg*b2), MFMA ----------
__global__ __launch_bounds__(256, 4) void gnn_node_out(
    const _Float16* __restrict__ hsum,  // [N_NODES][64] f16, permuted channels
    const int*      __restrict__ deg,   // [N_NODES]
    const float*    __restrict__ W2,    // [64][128]
    const float*    __restrict__ b2,    // [128]
    float*          __restrict__ out)   // [N_NODES][128]
{
    __shared__ __align__(16) unsigned short W2T[128][72];  // W2T[n][p]=W2[pi(p)][n]
    __shared__ float b2s[128];

    const int tid  = threadIdx.x;
    const int wave = tid >> 6;
    const int lane = tid & 63;
    const int q    = lane >> 4;
    const int m16  = lane & 15;

    for (int idx = tid; idx < 64 * 128; idx += 256) {
        int p = idx >> 7, n = idx & 127;
        // pi(p): dword d=p>>1, half e=p&1; d<16 -> ch d+16e; d>=16 -> d+16+16e
        int ch = (p >> 1) + 16 * (p & 1) + ((p >= 32) ? 16 : 0);
        W2T[n][p] = f2bf(W2[ch * 128 + n]);
    }
    if (tid < 128) b2s[tid] = b2[tid];
    __syncthreads();

    const int nodeBase = (blockIdx.x * 4 + wave) * 32;
    if (nodeBase >= N_NODES) return;

    f32x4 acc[2][8];
#pragma unroll
    for (int mt = 0; mt < 2; ++mt)
#pragma unroll
        for (int nt = 0; nt < 8; ++nt)
            acc[mt][nt] = (f32x4){0.0f, 0.0f, 0.0f, 0.0f};

#pragma unroll
    for (int kc = 0; kc < 2; ++kc) {
        bf16x8 af[2];
#pragma unroll
        for (int mt = 0; mt < 2; ++mt) {
            int node = nodeBase + mt * 16 + m16;
            if (node >= N_NODES) node = N_NODES - 1;
            f16x8 h = *reinterpret_cast<const f16x8*>(
                hsum + (size_t)node * HID_CH + kc * 32 + q * 8);
            union { bf16x8 v; unsigned short u[8]; } rr;
#pragma unroll
            for (int j = 0; j < 8; ++j) rr.u[j] = f2bf((float)h[j]);
            af[mt] = rr.v;
        }
#pragma unroll
        for (int nt = 0; nt < 8; ++nt) {
            bf16x8 bfr = *reinterpret_cast<const bf16x8*>(
                &W2T[nt * 16 + m16][kc * 32 + q * 8]);
            acc[0][nt] = __builtin_amdgcn_mfma_f32_16x16x32_bf16(af[0], bfr, acc[0][nt], 0, 0, 0);
            acc[1][nt] = __builtin_amdgcn_mfma_f32_16x16x32_bf16(af[1], bfr, acc[1][nt], 0, 0, 0);
        }
    }

#pragma unroll
    for (int mt = 0; mt < 2; ++mt) {
        float cc[4]; int nn[4];
#pragma unroll
        for (int r = 0; r < 4; ++r) {
            nn[r] = nodeBase + mt * 16 + q * 4 + r;
            cc[r] = (nn[r] < N_NODES) ? (float)deg[nn[r]] : 0.0f;
        }
#pragma unroll
        for (int nt = 0; nt < 8; ++nt) {
            int col = nt * 16 + m16;
            float bb = b2s[col];
#pragma unroll
            for (int r = 0; r < 4; ++r) {
                if (nn[r] < N_NODES) {
                    float v = acc[mt][nt][r] + cc[r] * bb;
                    out[(size_t)nn[r] * OUT_CH + col] = v > 0.0f ? v : 0.0f;
                }
            }
        }
    }
}

extern "C" void kernel_launch(void* const* d_in, const int* in_sizes, int n_in,
                              void* d_out, int out_size, void* d_ws, size_t ws_size,
                              hipStream_t stream) {
    const float* x  = (const float*)d_in[0];
    const int*   ei = (const int*)d_in[1];
    const float* ea = (const float*)d_in[2];
    const float* W1 = (const float*)d_in[3];
    const float* b1 = (const float*)d_in[4];
    const float* W2 = (const float*)d_in[5];
    const float* b2 = (const float*)d_in[6];
    float* out = (float*)d_out;

    // ws layout (bytes):
    // deg @0 (400,000) | st @400,000 (3,128) | ticket @403,200 (4)
    //   ^-- one contiguous 403,208B memset
    // hsum @403,264 (12.8M) | xb @13,203,264 (12.8M) | ntype @26,003,264 (100K)
    // off @26,103,296 (400K) | rec @26,503,360 (<=7.7M)   total ~34.2MB
    char* wsb = (char*)d_ws;
    int*                deg    = (int*)(wsb);
    unsigned long long* st     = (unsigned long long*)(wsb + 400000);
    int*                ticket = (int*)(wsb + 403200);
    unsigned int*       hsumU  = (unsigned int*)(wsb + 403264);
    unsigned short*     xb     = (unsigned short*)(wsb + 13203264);
    unsigned char*      ntype  = (unsigned char*)(wsb + 26003264);
    int*                off    = (int*)(wsb + 26103296);
    uint2*              rec    = (uint2*)(wsb + 26503360);

    // zero deg + scan state + ticket (ws re-poisoned to 0xAA every call)
    hipMemsetAsync(wsb, 0, 403208, stream);

    // fused x-convert + ntype + masked-degree hist + hsum zero
    gnn_prep_hist<<<N_EDGES / 256, 256, 0, stream>>>(
        x, xb, ntype, ei, ea, deg, (uint2*)hsumU);

    // single-pass decoupled-lookback exclusive scan (replaces 3 dispatches)
    gnn_scan1<<<NSCANBLK, 256, 0, stream>>>(deg, off, st, ticket);

    gnn_scatter<<<(N_EDGES + 255) / 256, 256, 0, stream>>>(ei, ea, ntype, off, rec);

    // R9 edge kernel: 1024 grid-stride blocks, 4/CU, lockstep tiles
    gnn_edge_sorted<<<1024, 256, 0, stream>>>(xb, rec, off, W1, b1, hsumU);

    gnn_node_out<<<(N_NODES + 127) / 128, 256, 0, stream>>>(
        (const _Float16*)hsumU, deg, W2, b2, out);
}